// Round 14
// baseline (88.747 us; speedup 1.0000x reference)
//
#include <hip/hip_runtime.h>
#include <hip/hip_bf16.h>
#include <stdint.h>

// STFT as GEMM with DFT symmetry fold (v13 = v12 with 32x32x16 MFMA GEMM):
//   unwindowed folds u[k]=f[k]+f[1024-k], v[k]=f[k]-f[1024-k] (k=1..511),
//   u[512]=f[512], v[512]=0, g0=0.08*f[0]:
//     re[t,n] = g0(t) + sum_{k=1..512} u[k]*basis[k][n+1]
//     im[t,n] =         sum_{k=1..512} v[k]*basis[k][514+n]
//   => two K=512 GEMMs (half the FLOPs). v12 passed @74.4us, absmax 0.5.
// v13 change (one variable): stft_gemm uses mfma_f32_32x32x16_bf16 —
//   half the MFMA instructions for the same FLOPs (8.07cy/32k-FLOP vs
//   2x4.85cy), same ds_read count, same XOR slot swizzle (bank pressure
//   identical), 128B-contiguous epilogue stores. Input frag layout: lane&31
//   -> row/col, lane>>5 -> k-group-of-8. C/D layout (m74/m101, HW-verified):
//   col=lane&31, row=(reg&3)+8*(reg>>2)+4*(lane>>5).
// Output: d_out = [re (8*4097*512) | im (8*4097*512)] fp32.

#define NX       2097152
#define NFRAMES  4097
#define NBATCH   8
#define KDIM     1024
#define BASIS_LD 1026
#define HALF_SZ  (NBATCH * NFRAMES * 512)

typedef __attribute__((ext_vector_type(8))) short bf16x8;
typedef __attribute__((ext_vector_type(4))) float f32x4;
typedef __attribute__((ext_vector_type(16))) float f32x16;

#define GLL16(src, dst) __builtin_amdgcn_global_load_lds( \
    (const __attribute__((address_space(1))) unsigned int*)(src), \
    (__attribute__((address_space(3))) unsigned int*)(dst), 16, 0, 0)

static __device__ __forceinline__ unsigned short f2bf(float f) {
    union { float f; uint32_t u; } v; v.f = f;
    uint32_t r = (v.u + 0x7FFFu + ((v.u >> 16) & 1u)) >> 16;  // RNE
    return (unsigned short)r;
}

static __device__ __forceinline__ int refl(int i) {
    if (i < 0) return -i;
    if (i >= NX) return 2 * (NX - 1) - i;
    return i;
}

// ======================= Tier-1 (symmetry-folded) ==========================
// ws layout: uv | Bimg2 | g0t
#define UV_BYTES    ((size_t)NBATCH * NFRAMES * 1024 * 2)        // 67,125,248
#define BIMG2_OFF   UV_BYTES
#define BIMG2_BYTES ((size_t)8 * 8 * 128 * 64 * 2)               // 1 MB
#define G0_OFF      (BIMG2_OFF + BIMG2_BYTES)
#define G0_BYTES    ((size_t)NBATCH * NFRAMES * 4)
#define WS_NEEDED2  (G0_OFF + G0_BYTES)

#define MTILES 33
#define NTILES 8
#define GRID   (NBATCH * MTILES * NTILES)  // 2112 = 8 * 264

#define NGROUPS 1025   // ceil(4097/4) frame-groups per batch

// Kernel: fused fold + g0 (v12 verbatim — passed). One block = 4 frames.
__global__ __launch_bounds__(256) void fold_pad2(
    const float* __restrict__ x,
    unsigned short* __restrict__ uv,
    float* __restrict__ g0t)
{
    __shared__ float w[2560];                // 10 KB
    const int blk = blockIdx.x;              // 0 .. 8*1025-1
    const int b = blk / NGROUPS, g = blk - b * NGROUPS;
    const int tid = threadIdx.x;
    const float* xb = x + (size_t)b * NX;
    const int base = g * 2048 - 512;         // first x index of group window

    if (g >= 1 && g <= 1023) {
        #pragma unroll
        for (int i = 0; i < 3; ++i) {
            int i4 = tid + i * 256;
            if (i4 < 640)
                *(float4*)&w[i4 * 4] = *(const float4*)(xb + base + i4 * 4);
        }
    } else {
        #pragma unroll
        for (int i = 0; i < 3; ++i) {
            int i4 = tid + i * 256;
            if (i4 < 640) {
                #pragma unroll
                for (int e = 0; e < 4; ++e)
                    w[i4 * 4 + e] = xb[refl(base + i4 * 4 + e)];
            }
        }
    }
    __syncthreads();

    const int k1 = 2 * tid + 1, k2 = k1 + 1;    // 1..511 / 2..512
    for (int f = 0; f < 4; ++f) {
        const int t = g * 4 + f;
        if (t > 4096) break;
        const float* wf = w + f * 512;          // frame window = wf[0..1023]
        float a1 = wf[k1],  b1v = wf[1024 - k1];
        float a2 = wf[k2],  b2v = wf[1024 - k2];
        float u1 = a1 + b1v, v1 = a1 - b1v;
        float u2 = (k2 == 512) ? a2 : (a2 + b2v);   // k=512 appears once
        float v2 = a2 - b2v;                         // = 0 at k2==512
        union { unsigned short s[2]; uint32_t u; } pu, pv;
        pu.s[0] = f2bf(u1); pu.s[1] = f2bf(u2);
        pv.s[0] = f2bf(v1); pv.s[1] = f2bf(v2);
        unsigned short* row = uv + ((size_t)b * NFRAMES + t) * 1024;
        *(uint32_t*)(row + 2 * tid)       = pu.u;
        *(uint32_t*)(row + 512 + 2 * tid) = pv.u;
        if (tid == 0) g0t[b * NFRAMES + t] = 0.08f * wf[0];
    }
}

// Kernel: basis rows 1..512 -> Bimg2 (v12 verbatim — passed).
__global__ void basis_to_img2(const float* __restrict__ basis,
                              unsigned short* __restrict__ Bimg2) {
    __shared__ float L[64][65];
    const int kt   = blockIdx.x & 7;      // 64-wide k tile (k = 1+kt*64+r)
    const int nt64 = blockIdx.x >> 3;     // 64-wide n tile (0..15)
    const int tid  = threadIdx.x;
    const int colbase = nt64 * 64 + (nt64 < 8 ? 1 : 2);  // re: +1, im: +2
    #pragma unroll
    for (int i = 0; i < 16; ++i) {
        int r = i * 4 + (tid >> 6);       // k-local
        int c = tid & 63;
        L[r][c] = basis[(size_t)(kt * 64 + r + 1) * BASIS_LD + colbase + c];
    }
    __syncthreads();
    #pragma unroll
    for (int i = 0; i < 16; ++i) {
        int nl  = i * 4 + (tid >> 6);
        int kkl = tid & 63;
        int gn  = nt64 * 64 + nl;         // 0..1023 (re 0..511 | im 512..1023)
        int nt2 = gn >> 7, row = gn & 127;
        int dslot = (kkl >> 3) ^ (row & 7);
        size_t off = ((size_t)(nt2 * 8 + kt) * 128 + row) * 64 + dslot * 8 + (kkl & 7);
        Bimg2[off] = f2bf(L[kkl][nl]);
    }
}

// Kernel: K=512 GEMM, v3-proven staging/swizzle, 32x32x16 MFMA.
// 4 waves (2x2), 64x64 quadrant/wave = 2x2 frags of 32x32.
__global__ __launch_bounds__(256, 4) void stft_gemm10(
    const unsigned short* __restrict__ uv,
    const unsigned short* __restrict__ Bimg2,
    const float* __restrict__ g0t,
    float* __restrict__ out)
{
    __shared__ unsigned short Al[128 * 64];  // 16 KB
    __shared__ unsigned short Bl[128 * 64];  // 16 KB

    const int bid = blockIdx.x;
    const int wg  = (bid & 7) * (GRID / 8) + (bid >> 3);   // bijective XCD swizzle
    const int ntile = wg & 7;
    const int mtile = (wg >> 3) % MTILES;
    const int batch = wg / (MTILES * NTILES);

    const int tid  = threadIdx.x;
    const int lane = tid & 63;
    const int wr   = tid >> 7;
    const int wc   = (tid >> 6) & 1;
    const int t0   = mtile * 128;
    const int ih   = (ntile >= 4);            // 0=re(u), 1=im(v)
    const int nh0  = (ntile & 3) * 128;       // col origin within half

    const unsigned short* __restrict__ uvb = uv + (size_t)batch * NFRAMES * 1024;
    const int l31 = lane & 31, l5 = lane >> 5;

    f32x16 acc[2][2];
    #pragma unroll
    for (int mi = 0; mi < 2; ++mi)
        #pragma unroll
        for (int ni = 0; ni < 2; ++ni)
            acc[mi][ni] = (f32x16)0.0f;

    for (int kt = 0; kt < 8; ++kt) {
        // ---- stage A: 128 rows x 64 k; linear LDS dest, swizzled source ----
        #pragma unroll
        for (int i = 0; i < 4; ++i) {
            int q   = i * 256 + tid;
            int row = q >> 3, d = q & 7;
            int tt  = t0 + row; if (tt > 4096) tt = 4096;   // tail clamp
            const unsigned short* src = uvb + (size_t)tt * 1024 + ih * 512
                + kt * 64 + ((d ^ (row & 7)) << 3);
            unsigned short* dst = Al + ((i * 256 + (tid & 192)) << 3);
            GLL16(src, dst);
        }
        // ---- stage B: pre-swizzled image -> purely linear copy ----
        {
            const unsigned short* srcb = Bimg2 + ((size_t)(ntile * 8 + kt)) * 8192;
            #pragma unroll
            for (int i = 0; i < 4; ++i) {
                unsigned short* dst = Bl + ((i * 256 + (tid & 192)) << 3);
                GLL16(srcb + ((i * 256 + tid) << 3), dst);
            }
        }
        __syncthreads();

        // ---- compute: 4 k-steps of 16; frag k-group = lane>>5 ----
        #pragma unroll
        for (int s = 0; s < 4; ++s) {
            bf16x8 af[2], bfr[2];
            #pragma unroll
            for (int mi = 0; mi < 2; ++mi) {
                int row  = wr * 64 + mi * 32 + l31;
                int slot = (s * 2 + l5) ^ (row & 7);
                af[mi] = *(const bf16x8*)(Al + row * 64 + (slot << 3));
            }
            #pragma unroll
            for (int ni = 0; ni < 2; ++ni) {
                int row  = wc * 64 + ni * 32 + l31;
                int slot = (s * 2 + l5) ^ (row & 7);
                bfr[ni] = *(const bf16x8*)(Bl + row * 64 + (slot << 3));
            }
            #pragma unroll
            for (int mi = 0; mi < 2; ++mi)
                #pragma unroll
                for (int ni = 0; ni < 2; ++ni)
                    acc[mi][ni] = __builtin_amdgcn_mfma_f32_32x32x16_bf16(
                        af[mi], bfr[ni], acc[mi][ni], 0, 0, 0);
        }
        __syncthreads();
    }

    // ---- epilogue: C/D (m74/m101): col=lane&31, row=(reg&3)+8*(reg>>2)+4*l5
    const float* g0b = g0t + (size_t)batch * NFRAMES;
    #pragma unroll
    for (int mi = 0; mi < 2; ++mi) {
        #pragma unroll
        for (int ni = 0; ni < 2; ++ni) {
            const int colb = nh0 + wc * 64 + ni * 32 + l31;
            #pragma unroll
            for (int reg = 0; reg < 16; ++reg) {
                const int t = t0 + wr * 64 + mi * 32
                            + (reg & 3) + 8 * (reg >> 2) + 4 * l5;
                if (t > 4096) continue;
                const float gval = (ih == 0) ? g0b[t] : 0.0f;
                const size_t o = (size_t)ih * HALF_SZ
                    + (size_t)batch * (NFRAMES * 512) + (size_t)t * 512 + colb;
                out[o] = acc[mi][ni][reg] + gval;
            }
        }
    }
}

// ======================= Tier-2 (proven round-4 path) ======================
#define PADLEN   2163712
#define XP_BYTES ((size_t)NBATCH * PADLEN * 2)
#define BIMG_OFF XP_BYTES
#define BIMG_BYTES ((size_t)8 * 16 * 8192 * 2)
#define WS_NEEDED_T2 (BIMG_OFF + BIMG_BYTES)

__global__ void convert_pad(const float* __restrict__ x,
                            unsigned short* __restrict__ xp) {
    const int per = PADLEN >> 2;
    int gid = blockIdx.x * 256 + threadIdx.x;
    int b   = gid / per;
    int i4  = (gid - b * per) << 2;
    const float* xb = x + (size_t)b * NX;
    int j = i4 - 512;
    unsigned short s0, s1, s2, s3;
    if (j >= 0 && j + 3 < NX) {
        float4 f = *(const float4*)(xb + j);
        s0 = f2bf(f.x); s1 = f2bf(f.y); s2 = f2bf(f.z); s3 = f2bf(f.w);
    } else {
        unsigned short ss[4];
        #pragma unroll
        for (int e = 0; e < 4; ++e) {
            int i = i4 + e;
            float v = 0.0f;
            if (i < NX + 1024) v = xb[refl(i - 512)];
            ss[e] = f2bf(v);
        }
        s0 = ss[0]; s1 = ss[1]; s2 = ss[2]; s3 = ss[3];
    }
    union { unsigned short s[4]; uint2 u; } p;
    p.s[0] = s0; p.s[1] = s1; p.s[2] = s2; p.s[3] = s3;
    *(uint2*)(xp + (size_t)b * PADLEN + i4) = p.u;
}

__global__ void basis_to_img(const float* __restrict__ basis,
                             unsigned short* __restrict__ Bimg) {
    __shared__ float L[64][65];
    const int kt  = blockIdx.x & 15;
    const int nt  = blockIdx.x >> 4;
    const int tid = threadIdx.x;
    const int colbase = nt * 64 + (nt < 8 ? 1 : 2);
    #pragma unroll
    for (int i = 0; i < 16; ++i) {
        int r = i * 4 + (tid >> 6);
        int c = tid & 63;
        L[r][c] = basis[(size_t)(kt * 64 + r) * BASIS_LD + colbase + c];
    }
    __syncthreads();
    #pragma unroll
    for (int i = 0; i < 16; ++i) {
        int nl = i * 4 + (tid >> 6);
        int kk = tid & 63;
        int n  = nt * 64 + nl;
        int nt2 = n >> 7, row = n & 127;
        int dslot = (kk >> 3) ^ (row & 7);
        size_t off = ((size_t)(nt2 * 16 + kt) * 128 + row) * 64 + dslot * 8 + (kk & 7);
        Bimg[off] = f2bf(L[kk][nl]);
    }
}

__global__ __launch_bounds__(256, 4) void stft_gemm2(
    const unsigned short* __restrict__ xp,
    const unsigned short* __restrict__ Bimg,
    float* __restrict__ out)
{
    __shared__ unsigned short Al[128 * 64];
    __shared__ unsigned short Bl[128 * 64];
    const int bid = blockIdx.x;
    const int wg  = (bid & 7) * (GRID / 8) + (bid >> 3);
    const int ntile = wg & 7;
    const int mtile = (wg >> 3) % MTILES;
    const int batch = wg / (MTILES * NTILES);
    const int tid  = threadIdx.x;
    const int lane = tid & 63;
    const int wr   = tid >> 7;
    const int wc   = (tid >> 6) & 1;
    const int t0   = mtile * 128;
    const int n0   = ntile * 128;
    const unsigned short* __restrict__ xpb = xp + (size_t)batch * PADLEN;
    const int l15 = lane & 15, l4 = lane >> 4;
    const unsigned short* __restrict__ bt  = Bimg + (size_t)ntile * 16 * 8192;

    f32x4 acc[4][4];
    #pragma unroll
    for (int m = 0; m < 4; ++m)
        #pragma unroll
        for (int n = 0; n < 4; ++n)
            acc[m][n] = (f32x4)0.0f;

    for (int k0 = 0; k0 < KDIM; k0 += 64) {
        #pragma unroll
        for (int i = 0; i < 4; ++i) {
            int q   = i * 256 + tid;
            int row = q >> 3, d = q & 7;
            const unsigned short* src =
                xpb + (size_t)(t0 + row) * 512 + k0 + ((d ^ (row & 7)) << 3);
            unsigned short* dst = Al + ((i * 256 + (tid & 192)) << 3);
            GLL16(src, dst);
        }
        {
            const unsigned short* srcb = bt + (size_t)(k0 >> 6) * 8192;
            #pragma unroll
            for (int i = 0; i < 4; ++i) {
                unsigned short* dst = Bl + ((i * 256 + (tid & 192)) << 3);
                GLL16(srcb + ((i * 256 + tid) << 3), dst);
            }
        }
        __syncthreads();
        #pragma unroll
        for (int ks = 0; ks < 2; ++ks) {
            const int slot0 = ks * 4 + l4;
            bf16x8 af[4], bfr[4];
            #pragma unroll
            for (int m = 0; m < 4; ++m) {
                int row = wr * 64 + m * 16 + l15;
                af[m] = *(const bf16x8*)(Al + row * 64 + ((slot0 ^ (row & 7)) << 3));
            }
            #pragma unroll
            for (int n = 0; n < 4; ++n) {
                int row = wc * 64 + n * 16 + l15;
                bfr[n] = *(const bf16x8*)(Bl + row * 64 + ((slot0 ^ (row & 7)) << 3));
            }
            #pragma unroll
            for (int m = 0; m < 4; ++m)
                #pragma unroll
                for (int n = 0; n < 4; ++n)
                    acc[m][n] = __builtin_amdgcn_mfma_f32_16x16x32_bf16(
                        af[m], bfr[n], acc[m][n], 0, 0, 0);
        }
        __syncthreads();
    }
    const int colb = n0 + wc * 64 + l15;
    #pragma unroll
    for (int m = 0; m < 4; ++m) {
        const int trow0 = t0 + wr * 64 + m * 16 + (l4 << 2);
        #pragma unroll
        for (int r = 0; r < 4; ++r) {
            const int t = trow0 + r;
            if (t > 4096) continue;
            const size_t rowbase = (size_t)batch * (NFRAMES * 512) + (size_t)t * 512;
            #pragma unroll
            for (int n = 0; n < 4; ++n) {
                const int gc = colb + n * 16;
                const size_t o = (size_t)(gc >> 9) * HALF_SZ + rowbase + (gc & 511);
                out[o] = acc[m][n][r];
            }
        }
    }
}

extern "C" void kernel_launch(void* const* d_in, const int* in_sizes, int n_in,
                              void* d_out, int out_size, void* d_ws, size_t ws_size,
                              hipStream_t stream) {
    const float* x     = (const float*)d_in[0];
    const float* basis = (const float*)d_in[1];
    float* out = (float*)d_out;

    if (ws_size >= WS_NEEDED2) {
        unsigned short* uv    = (unsigned short*)d_ws;
        unsigned short* Bimg2 = (unsigned short*)((char*)d_ws + BIMG2_OFF);
        float*          g0t   = (float*)((char*)d_ws + G0_OFF);
        fold_pad2<<<NBATCH * NGROUPS, 256, 0, stream>>>(x, uv, g0t);
        basis_to_img2<<<128, 256, 0, stream>>>(basis, Bimg2);
        stft_gemm10<<<GRID, 256, 0, stream>>>(uv, Bimg2, g0t, out);
    } else if (ws_size >= WS_NEEDED_T2) {
        // proven round-4 path (95.6 us)
        unsigned short* xp   = (unsigned short*)d_ws;
        unsigned short* Bimg = (unsigned short*)((char*)d_ws + BIMG_OFF);
        convert_pad<<<(NBATCH * (PADLEN >> 2)) / 256, 256, 0, stream>>>(x, xp);
        basis_to_img<<<256, 256, 0, stream>>>(basis, Bimg);
        stft_gemm2<<<GRID, 256, 0, stream>>>(xp, Bimg, out);
    }
}

// Round 15
// 74.884 us; speedup vs baseline: 1.1851x; 1.1851x over previous
//
#include <hip/hip_runtime.h>
#include <hip/hip_bf16.h>
#include <stdint.h>

// STFT as GEMM with DFT symmetry fold (v14 = exact revert to v12, the best
// verified configuration: 74.4us total, absmax 0.5):
//   unwindowed folds u[k]=f[k]+f[1024-k], v[k]=f[k]-f[1024-k] (k=1..511),
//   u[512]=f[512], v[512]=0, g0=0.08*f[0]:
//     re[t,n] = g0(t) + sum_{k=1..512} u[k]*basis[k][n+1]
//     im[t,n] =         sum_{k=1..512} v[k]*basis[k][514+n]
//   => two K=512 GEMMs (half the FLOPs), v3-proven 16x16x32 MFMA structure
//   (16 independent accumulators = enough ILP; the 32x32 variant's 4 chained
//   accumulators starved the matrix pipe, v13 post-mortem).
// Components: fold_pad2 (LDS-windowed fused fold+g0, ~BW floor),
// basis_to_img2 (pre-swizzled B image), stft_gemm9 (GLL16 + XOR swizzle,
// 0 bank conflicts, 4 blocks/CU).
// Output: d_out = [re (8*4097*512) | im (8*4097*512)] fp32.

#define NX       2097152
#define NFRAMES  4097
#define NBATCH   8
#define KDIM     1024
#define BASIS_LD 1026
#define HALF_SZ  (NBATCH * NFRAMES * 512)

typedef __attribute__((ext_vector_type(8))) short bf16x8;
typedef __attribute__((ext_vector_type(4))) float f32x4;

#define GLL16(src, dst) __builtin_amdgcn_global_load_lds( \
    (const __attribute__((address_space(1))) unsigned int*)(src), \
    (__attribute__((address_space(3))) unsigned int*)(dst), 16, 0, 0)

static __device__ __forceinline__ unsigned short f2bf(float f) {
    union { float f; uint32_t u; } v; v.f = f;
    uint32_t r = (v.u + 0x7FFFu + ((v.u >> 16) & 1u)) >> 16;  // RNE
    return (unsigned short)r;
}

static __device__ __forceinline__ int refl(int i) {
    if (i < 0) return -i;
    if (i >= NX) return 2 * (NX - 1) - i;
    return i;
}

// ======================= Tier-1 (symmetry-folded) ==========================
// ws layout: uv | Bimg2 | g0t
#define UV_BYTES    ((size_t)NBATCH * NFRAMES * 1024 * 2)        // 67,125,248
#define BIMG2_OFF   UV_BYTES
#define BIMG2_BYTES ((size_t)8 * 8 * 128 * 64 * 2)               // 1 MB
#define G0_OFF      (BIMG2_OFF + BIMG2_BYTES)
#define G0_BYTES    ((size_t)NBATCH * NFRAMES * 4)
#define WS_NEEDED2  (G0_OFF + G0_BYTES)

#define MTILES 33
#define NTILES 8
#define GRID   (NBATCH * MTILES * NTILES)  // 2112 = 8 * 264

#define NGROUPS 1025   // ceil(4097/4) frame-groups per batch

// Kernel: fused fold + g0. One block = 4 consecutive frames of one batch.
// LDS holds the union of their windows: 2560 floats (halos shared).
__global__ __launch_bounds__(256) void fold_pad2(
    const float* __restrict__ x,
    unsigned short* __restrict__ uv,
    float* __restrict__ g0t)
{
    __shared__ float w[2560];                // 10 KB
    const int blk = blockIdx.x;              // 0 .. 8*1025-1
    const int b = blk / NGROUPS, g = blk - b * NGROUPS;
    const int tid = threadIdx.x;
    const float* xb = x + (size_t)b * NX;
    const int base = g * 2048 - 512;         // first x index of group window

    if (g >= 1 && g <= 1023) {
        // interior: aligned float4, fully in-bounds
        #pragma unroll
        for (int i = 0; i < 3; ++i) {
            int i4 = tid + i * 256;
            if (i4 < 640)
                *(float4*)&w[i4 * 4] = *(const float4*)(xb + base + i4 * 4);
        }
    } else {
        // edge groups (g=0 left reflect, g=1024 right reflect)
        #pragma unroll
        for (int i = 0; i < 3; ++i) {
            int i4 = tid + i * 256;
            if (i4 < 640) {
                #pragma unroll
                for (int e = 0; e < 4; ++e)
                    w[i4 * 4 + e] = xb[refl(base + i4 * 4 + e)];
            }
        }
    }
    __syncthreads();

    const int k1 = 2 * tid + 1, k2 = k1 + 1;    // 1..511 / 2..512
    for (int f = 0; f < 4; ++f) {
        const int t = g * 4 + f;
        if (t > 4096) break;
        const float* wf = w + f * 512;          // frame window = wf[0..1023]
        float a1 = wf[k1],  b1v = wf[1024 - k1];
        float a2 = wf[k2],  b2v = wf[1024 - k2];
        float u1 = a1 + b1v, v1 = a1 - b1v;
        float u2 = (k2 == 512) ? a2 : (a2 + b2v);   // k=512 appears once
        float v2 = a2 - b2v;                         // = 0 at k2==512
        union { unsigned short s[2]; uint32_t u; } pu, pv;
        pu.s[0] = f2bf(u1); pu.s[1] = f2bf(u2);
        pv.s[0] = f2bf(v1); pv.s[1] = f2bf(v2);
        unsigned short* row = uv + ((size_t)b * NFRAMES + t) * 1024;
        *(uint32_t*)(row + 2 * tid)       = pu.u;
        *(uint32_t*)(row + 512 + 2 * tid) = pv.u;
        if (tid == 0) g0t[b * NFRAMES + t] = 0.08f * wf[0];
    }
}

// Kernel: basis rows 1..512 -> Bimg2 [nt2(8)][kt(8)][row(128)][slot(8)][8],
// slot = (klocal>>3) ^ (row&7): pre-swizzled for linear global_load_lds.
__global__ void basis_to_img2(const float* __restrict__ basis,
                              unsigned short* __restrict__ Bimg2) {
    __shared__ float L[64][65];
    const int kt   = blockIdx.x & 7;      // 64-wide k tile (k = 1+kt*64+r)
    const int nt64 = blockIdx.x >> 3;     // 64-wide n tile (0..15)
    const int tid  = threadIdx.x;
    const int colbase = nt64 * 64 + (nt64 < 8 ? 1 : 2);  // re: +1, im: +2
    #pragma unroll
    for (int i = 0; i < 16; ++i) {
        int r = i * 4 + (tid >> 6);       // k-local
        int c = tid & 63;
        L[r][c] = basis[(size_t)(kt * 64 + r + 1) * BASIS_LD + colbase + c];
    }
    __syncthreads();
    #pragma unroll
    for (int i = 0; i < 16; ++i) {
        int nl  = i * 4 + (tid >> 6);
        int kkl = tid & 63;
        int gn  = nt64 * 64 + nl;         // 0..1023 (re 0..511 | im 512..1023)
        int nt2 = gn >> 7, row = gn & 127;
        int dslot = (kkl >> 3) ^ (row & 7);
        size_t off = ((size_t)(nt2 * 8 + kt) * 128 + row) * 64 + dslot * 8 + (kkl & 7);
        Bimg2[off] = f2bf(L[kkl][nl]);
    }
}

// Kernel: K=512 GEMM, v3 structure verbatim (single-buffered, GLL16 + XOR
// chunk swizzle, 2 barriers/K-tile, 4 blocks/CU). ntile<4: re (u half),
// ntile>=4: im (v half). g0 added in epilogue for re.
__global__ __launch_bounds__(256, 4) void stft_gemm9(
    const unsigned short* __restrict__ uv,
    const unsigned short* __restrict__ Bimg2,
    const float* __restrict__ g0t,
    float* __restrict__ out)
{
    __shared__ unsigned short Al[128 * 64];  // 16 KB
    __shared__ unsigned short Bl[128 * 64];  // 16 KB

    const int bid = blockIdx.x;
    const int wg  = (bid & 7) * (GRID / 8) + (bid >> 3);   // bijective XCD swizzle
    const int ntile = wg & 7;
    const int mtile = (wg >> 3) % MTILES;
    const int batch = wg / (MTILES * NTILES);

    const int tid  = threadIdx.x;
    const int lane = tid & 63;
    const int wr   = tid >> 7;
    const int wc   = (tid >> 6) & 1;
    const int t0   = mtile * 128;
    const int ih   = (ntile >= 4);            // 0=re(u), 1=im(v)
    const int nh0  = (ntile & 3) * 128;       // col origin within half

    const unsigned short* __restrict__ uvb = uv + (size_t)batch * NFRAMES * 1024;
    const int l15 = lane & 15, l4 = lane >> 4;

    f32x4 acc[4][4];
    #pragma unroll
    for (int m = 0; m < 4; ++m)
        #pragma unroll
        for (int n = 0; n < 4; ++n)
            acc[m][n] = (f32x4)0.0f;

    for (int kt = 0; kt < 8; ++kt) {
        // ---- stage A: 128 rows x 64 k; linear LDS dest, swizzled source ----
        #pragma unroll
        for (int i = 0; i < 4; ++i) {
            int q   = i * 256 + tid;
            int row = q >> 3, d = q & 7;
            int tt  = t0 + row; if (tt > 4096) tt = 4096;   // tail clamp
            const unsigned short* src = uvb + (size_t)tt * 1024 + ih * 512
                + kt * 64 + ((d ^ (row & 7)) << 3);
            unsigned short* dst = Al + ((i * 256 + (tid & 192)) << 3);
            GLL16(src, dst);
        }
        // ---- stage B: pre-swizzled image -> purely linear copy ----
        {
            const unsigned short* srcb = Bimg2 + ((size_t)(ntile * 8 + kt)) * 8192;
            #pragma unroll
            for (int i = 0; i < 4; ++i) {
                unsigned short* dst = Bl + ((i * 256 + (tid & 192)) << 3);
                GLL16(srcb + ((i * 256 + tid) << 3), dst);
            }
        }
        __syncthreads();

        #pragma unroll
        for (int ks = 0; ks < 2; ++ks) {
            bf16x8 af[4], bfr[4];
            #pragma unroll
            for (int m = 0; m < 4; ++m) {
                int row  = wr * 64 + m * 16 + l15;
                int slot = (ks * 4 + l4) ^ (row & 7);
                af[m] = *(const bf16x8*)(Al + row * 64 + (slot << 3));
            }
            #pragma unroll
            for (int n = 0; n < 4; ++n) {
                int row  = wc * 64 + n * 16 + l15;
                int slot = (ks * 4 + l4) ^ (row & 7);
                bfr[n] = *(const bf16x8*)(Bl + row * 64 + (slot << 3));
            }
            #pragma unroll
            for (int m = 0; m < 4; ++m)
                #pragma unroll
                for (int n = 0; n < 4; ++n)
                    acc[m][n] = __builtin_amdgcn_mfma_f32_16x16x32_bf16(
                        af[m], bfr[n], acc[m][n], 0, 0, 0);
        }
        __syncthreads();
    }

    // ---- epilogue: C/D layout (m89): col = lane&15, row = (lane>>4)*4 + reg
    const int colb = nh0 + wc * 64 + l15;
    const float* g0b = g0t + (size_t)batch * NFRAMES;
    #pragma unroll
    for (int m = 0; m < 4; ++m) {
        const int trow0 = t0 + wr * 64 + m * 16 + (l4 << 2);
        #pragma unroll
        for (int r = 0; r < 4; ++r) {
            const int t = trow0 + r;
            if (t > 4096) continue;
            const float gval = (ih == 0) ? g0b[t] : 0.0f;
            const size_t rowbase = (size_t)ih * HALF_SZ
                + (size_t)batch * (NFRAMES * 512) + (size_t)t * 512;
            #pragma unroll
            for (int n = 0; n < 4; ++n)
                out[rowbase + colb + n * 16] = acc[m][n][r] + gval;
        }
    }
}

// ======================= Tier-2 (proven round-4 path) ======================
#define PADLEN   2163712
#define XP_BYTES ((size_t)NBATCH * PADLEN * 2)
#define BIMG_OFF XP_BYTES
#define BIMG_BYTES ((size_t)8 * 16 * 8192 * 2)
#define WS_NEEDED_T2 (BIMG_OFF + BIMG_BYTES)

__global__ void convert_pad(const float* __restrict__ x,
                            unsigned short* __restrict__ xp) {
    const int per = PADLEN >> 2;
    int gid = blockIdx.x * 256 + threadIdx.x;
    int b   = gid / per;
    int i4  = (gid - b * per) << 2;
    const float* xb = x + (size_t)b * NX;
    int j = i4 - 512;
    unsigned short s0, s1, s2, s3;
    if (j >= 0 && j + 3 < NX) {
        float4 f = *(const float4*)(xb + j);
        s0 = f2bf(f.x); s1 = f2bf(f.y); s2 = f2bf(f.z); s3 = f2bf(f.w);
    } else {
        unsigned short ss[4];
        #pragma unroll
        for (int e = 0; e < 4; ++e) {
            int i = i4 + e;
            float v = 0.0f;
            if (i < NX + 1024) v = xb[refl(i - 512)];
            ss[e] = f2bf(v);
        }
        s0 = ss[0]; s1 = ss[1]; s2 = ss[2]; s3 = ss[3];
    }
    union { unsigned short s[4]; uint2 u; } p;
    p.s[0] = s0; p.s[1] = s1; p.s[2] = s2; p.s[3] = s3;
    *(uint2*)(xp + (size_t)b * PADLEN + i4) = p.u;
}

__global__ void basis_to_img(const float* __restrict__ basis,
                             unsigned short* __restrict__ Bimg) {
    __shared__ float L[64][65];
    const int kt  = blockIdx.x & 15;
    const int nt  = blockIdx.x >> 4;
    const int tid = threadIdx.x;
    const int colbase = nt * 64 + (nt < 8 ? 1 : 2);
    #pragma unroll
    for (int i = 0; i < 16; ++i) {
        int r = i * 4 + (tid >> 6);
        int c = tid & 63;
        L[r][c] = basis[(size_t)(kt * 64 + r) * BASIS_LD + colbase + c];
    }
    __syncthreads();
    #pragma unroll
    for (int i = 0; i < 16; ++i) {
        int nl = i * 4 + (tid >> 6);
        int kk = tid & 63;
        int n  = nt * 64 + nl;
        int nt2 = n >> 7, row = n & 127;
        int dslot = (kk >> 3) ^ (row & 7);
        size_t off = ((size_t)(nt2 * 16 + kt) * 128 + row) * 64 + dslot * 8 + (kk & 7);
        Bimg[off] = f2bf(L[kk][nl]);
    }
}

__global__ __launch_bounds__(256, 4) void stft_gemm2(
    const unsigned short* __restrict__ xp,
    const unsigned short* __restrict__ Bimg,
    float* __restrict__ out)
{
    __shared__ unsigned short Al[128 * 64];
    __shared__ unsigned short Bl[128 * 64];
    const int bid = blockIdx.x;
    const int wg  = (bid & 7) * (GRID / 8) + (bid >> 3);
    const int ntile = wg & 7;
    const int mtile = (wg >> 3) % MTILES;
    const int batch = wg / (MTILES * NTILES);
    const int tid  = threadIdx.x;
    const int lane = tid & 63;
    const int wr   = tid >> 7;
    const int wc   = (tid >> 6) & 1;
    const int t0   = mtile * 128;
    const int n0   = ntile * 128;
    const unsigned short* __restrict__ xpb = xp + (size_t)batch * PADLEN;
    const int l15 = lane & 15, l4 = lane >> 4;
    const unsigned short* __restrict__ bt  = Bimg + (size_t)ntile * 16 * 8192;

    f32x4 acc[4][4];
    #pragma unroll
    for (int m = 0; m < 4; ++m)
        #pragma unroll
        for (int n = 0; n < 4; ++n)
            acc[m][n] = (f32x4)0.0f;

    for (int k0 = 0; k0 < KDIM; k0 += 64) {
        #pragma unroll
        for (int i = 0; i < 4; ++i) {
            int q   = i * 256 + tid;
            int row = q >> 3, d = q & 7;
            const unsigned short* src =
                xpb + (size_t)(t0 + row) * 512 + k0 + ((d ^ (row & 7)) << 3);
            unsigned short* dst = Al + ((i * 256 + (tid & 192)) << 3);
            GLL16(src, dst);
        }
        {
            const unsigned short* srcb = bt + (size_t)(k0 >> 6) * 8192;
            #pragma unroll
            for (int i = 0; i < 4; ++i) {
                unsigned short* dst = Bl + ((i * 256 + (tid & 192)) << 3);
                GLL16(srcb + ((i * 256 + tid) << 3), dst);
            }
        }
        __syncthreads();
        #pragma unroll
        for (int ks = 0; ks < 2; ++ks) {
            const int slot0 = ks * 4 + l4;
            bf16x8 af[4], bfr[4];
            #pragma unroll
            for (int m = 0; m < 4; ++m) {
                int row = wr * 64 + m * 16 + l15;
                af[m] = *(const bf16x8*)(Al + row * 64 + ((slot0 ^ (row & 7)) << 3));
            }
            #pragma unroll
            for (int n = 0; n < 4; ++n) {
                int row = wc * 64 + n * 16 + l15;
                bfr[n] = *(const bf16x8*)(Bl + row * 64 + ((slot0 ^ (row & 7)) << 3));
            }
            #pragma unroll
            for (int m = 0; m < 4; ++m)
                #pragma unroll
                for (int n = 0; n < 4; ++n)
                    acc[m][n] = __builtin_amdgcn_mfma_f32_16x16x32_bf16(
                        af[m], bfr[n], acc[m][n], 0, 0, 0);
        }
        __syncthreads();
    }
    const int colb = n0 + wc * 64 + l15;
    #pragma unroll
    for (int m = 0; m < 4; ++m) {
        const int trow0 = t0 + wr * 64 + m * 16 + (l4 << 2);
        #pragma unroll
        for (int r = 0; r < 4; ++r) {
            const int t = trow0 + r;
            if (t > 4096) continue;
            const size_t rowbase = (size_t)batch * (NFRAMES * 512) + (size_t)t * 512;
            #pragma unroll
            for (int n = 0; n < 4; ++n) {
                const int gc = colb + n * 16;
                const size_t o = (size_t)(gc >> 9) * HALF_SZ + rowbase + (gc & 511);
                out[o] = acc[m][n][r];
            }
        }
    }
}

extern "C" void kernel_launch(void* const* d_in, const int* in_sizes, int n_in,
                              void* d_out, int out_size, void* d_ws, size_t ws_size,
                              hipStream_t stream) {
    const float* x     = (const float*)d_in[0];
    const float* basis = (const float*)d_in[1];
    float* out = (float*)d_out;

    if (ws_size >= WS_NEEDED2) {
        unsigned short* uv    = (unsigned short*)d_ws;
        unsigned short* Bimg2 = (unsigned short*)((char*)d_ws + BIMG2_OFF);
        float*          g0t   = (float*)((char*)d_ws + G0_OFF);
        fold_pad2<<<NBATCH * NGROUPS, 256, 0, stream>>>(x, uv, g0t);
        basis_to_img2<<<128, 256, 0, stream>>>(basis, Bimg2);
        stft_gemm9<<<GRID, 256, 0, stream>>>(uv, Bimg2, g0t, out);
    } else if (ws_size >= WS_NEEDED_T2) {
        // proven round-4 path (95.6 us)
        unsigned short* xp   = (unsigned short*)d_ws;
        unsigned short* Bimg = (unsigned short*)((char*)d_ws + BIMG_OFF);
        convert_pad<<<(NBATCH * (PADLEN >> 2)) / 256, 256, 0, stream>>>(x, xp);
        basis_to_img<<<256, 256, 0, stream>>>(basis, Bimg);
        stft_gemm2<<<GRID, 256, 0, stream>>>(xp, Bimg, out);
    }
}